// Round 9
// baseline (774.919 us; speedup 1.0000x reference)
//
#include <hip/hip_runtime.h>
#include <math.h>

// Problem constants
#define BB 4
#define CINC 256
#define COUTC 128
#define HH 64
#define WW 64
#define OHH 128
#define OWW 128

// ---------------- K0t: transpose dcn_w [o][c][q] -> w_t[(c*9+q)][o]
__global__ __launch_bounds__(256) void k0t(const float* __restrict__ dcn_w, float* __restrict__ w_t) {
  int tid = blockIdx.x * 256 + threadIdx.x;
  if (tid >= COUTC * CINC * 9) return;
  int ck = tid >> 7;
  int o = tid & 127;
  w_t[tid] = dcn_w[o * (CINC * 9) + ck];
}

// ---------------- K0u: transpose up_w -> wt4[tt][i][o][s]
__global__ __launch_bounds__(256) void k0u(const float* __restrict__ up_w, float* __restrict__ wt4) {
  int tid = blockIdx.x * 256 + threadIdx.x;
  if (tid >= 4 * COUTC * COUTC * 4) return;
  int s = tid & 3;
  int o = (tid >> 2) & 127;
  int i = (tid >> 9) & 127;
  int tt = tid >> 16;
  wt4[tid] = up_w[((i * COUTC + o) * 4 + (3 - tt)) * 4 + (3 - s)];
}

// ---------------- K1p: offset conv split-K partials. grid (4,64,4)=(cc,h,b), 256 thr.
__global__ __launch_bounds__(256) void k1p(const float* __restrict__ x,
                                           const float* __restrict__ off_w,
                                           float* __restrict__ part) {
  int cc = blockIdx.x, h = blockIdx.y, b = blockIdx.z;
  __shared__ float xs[3 * 32 * 66];
  int t = threadIdx.x;
  int tw = t & 63;
  int tg = __builtin_amdgcn_readfirstlane(t >> 6);

  float acc[7];
#pragma unroll
  for (int j = 0; j < 7; j++) acc[j] = 0.f;

  for (int cs = 0; cs < 2; cs++) {
    int c0 = cc * 64 + cs * 32;
    __syncthreads();
    for (int e = t; e < 3 * 32 * 66; e += 256) {
      int r = e / (32 * 66);
      int rem = e - r * (32 * 66);
      int c = rem / 66;
      int wi = rem - c * 66;
      int row = h - 1 + r;
      int col = wi - 1;
      float v = 0.f;
      if (row >= 0 && row < HH && col >= 0 && col < WW)
        v = x[((b * CINC + c0 + c) * HH + row) * WW + col];
      xs[(r * 32 + c) * 66 + wi] = v;
    }
    __syncthreads();
    for (int c = 0; c < 32; c++) {
      float xv[9];
#pragma unroll
      for (int r = 0; r < 3; r++)
#pragma unroll
        for (int dx = 0; dx < 3; dx++)
          xv[r * 3 + dx] = xs[(r * 32 + c) * 66 + tw + dx];
#pragma unroll
      for (int j = 0; j < 7; j++) {
        int oc = tg + 4 * j;
        if (oc < 27) {
          const float* wp = off_w + (oc * CINC + c0 + c) * 9;  // uniform -> s_load
#pragma unroll
          for (int q = 0; q < 9; q++) acc[j] = fmaf(xv[q], wp[q], acc[j]);
        }
      }
    }
  }

#pragma unroll
  for (int j = 0; j < 7; j++) {
    int oc = tg + 4 * j;
    if (oc < 27)
      part[((cc * BB + b) * 27 + oc) * 4096 + h * 64 + tw] = acc[j];
  }
}

// ---------------- K1r: reduce 4 partials + bias -> py/px/m
__global__ __launch_bounds__(256) void k1r(const float* __restrict__ part,
                                           const float* __restrict__ off_b,
                                           float* __restrict__ pyg,
                                           float* __restrict__ pxg,
                                           float* __restrict__ mg) {
  int tid = blockIdx.x * 256 + threadIdx.x;
  if (tid >= BB * 27 * HH * WW) return;
  int w = tid & 63;
  int h = (tid >> 6) & 63;
  int oc = (tid >> 12) % 27;
  int b = tid / (27 * 4096);
  int sp = tid & 4095;

  float v = off_b[oc];
#pragma unroll
  for (int cc = 0; cc < 4; cc++)
    v += part[((cc * BB + b) * 27 + oc) * 4096 + sp];

  int k = oc % 9;
  int gi = ((b * 9 + k) * HH + h) * WW + w;
  if (oc < 9) {
    pyg[gi] = v + (float)(oc / 3) - 1.f + (float)h;
  } else if (oc < 18) {
    pxg[gi] = v + (float)((oc - 9) % 3) - 1.f + (float)w;
  } else {
    mg[gi] = 1.f / (1.f + expf(-v));
  }
}

// ---------------- K2p: deformable conv, split-K(4) GEMM. grid (4,64,4)=(ks,h,b).
// Block: 64 px (row h) x 128 cout x 64 input channels (8 chunks of 8).
// LDS: only samples (25.3 KB) -> 4+ blocks/CU. Weights read direct from L2
// (16 lanes share each float4 -> 128 B/wave coalesced).
__device__ __forceinline__ float sampf(const float* __restrict__ xp, int yi, int xi) {
  if (yi < 0 || yi >= HH || xi < 0 || xi >= WW) return 0.f;
  return xp[yi * WW + xi];
}

__global__ __launch_bounds__(256) void k2p(const float* __restrict__ x,
                                           const float* __restrict__ w_t,
                                           const float* __restrict__ pyg,
                                           const float* __restrict__ pxg,
                                           const float* __restrict__ mg,
                                           float* __restrict__ part2) {
  int ks = blockIdx.x, h = blockIdx.y, b = blockIdx.z;
  __shared__ __align__(16) float posS[3 * 576];   // py | px | m, each [9][64]
  __shared__ __align__(16) float scol[72 * 64];   // (8ch x 9k) x 64 px
  int t = threadIdx.x;

  for (int e = t; e < 576; e += 256) {
    int k = e >> 6, wl = e & 63;
    int gi = ((b * 9 + k) * HH + h) * WW + wl;
    posS[e] = pyg[gi];
    posS[576 + e] = pxg[gi];
    posS[1152 + e] = mg[gi];
  }

  float acc[8][4];
#pragma unroll
  for (int i = 0; i < 8; i++)
#pragma unroll
    for (int j = 0; j < 4; j++) acc[i][j] = 0.f;

  int co0 = (t >> 4) * 8;   // 0..120 (16 lanes share)
  int w0 = (t & 15) * 4;    // 0..60
  const float* xpb = x + b * CINC * HH * WW;

  for (int cs = 0; cs < 8; cs++) {
    int c0 = ks * 64 + cs * 8;
    __syncthreads();
    // gather samples into regs (18/thread), then commit to LDS
    float sreg[18];
#pragma unroll
    for (int j = 0; j < 18; j++) {
      int e = t + 256 * j;
      int ck = e >> 6, wl = e & 63;
      int c = c0 + ck / 9;
      int k = ck % 9;
      float py = posS[k * 64 + wl];
      float px = posS[576 + k * 64 + wl];
      float m = posS[1152 + k * 64 + wl];
      float y0f = floorf(py), x0f = floorf(px);
      float wy = py - y0f, wx = px - x0f;
      int y0 = (int)y0f, x0 = (int)x0f;
      const float* xp = xpb + c * HH * WW;
      float v00 = sampf(xp, y0, x0);
      float v01 = sampf(xp, y0, x0 + 1);
      float v10 = sampf(xp, y0 + 1, x0);
      float v11 = sampf(xp, y0 + 1, x0 + 1);
      float v = v00 * (1.f - wy) * (1.f - wx) + v01 * (1.f - wy) * wx +
                v10 * wy * (1.f - wx) + v11 * wy * wx;
      sreg[j] = v * m;
    }
#pragma unroll
    for (int j = 0; j < 18; j++) scol[t + 256 * j] = sreg[j];
    __syncthreads();
    // compute: 72 ck x (8 cout x 4 px); weights direct from L2
    const float* wrow = w_t + (c0 * 9) * 128 + co0;
#pragma unroll 4
    for (int ck = 0; ck < 72; ck++) {
      float4 sv = *(const float4*)&scol[ck * 64 + w0];
      float4 wva = *(const float4*)(wrow + ck * 128);
      float4 wvb = *(const float4*)(wrow + ck * 128 + 4);
      acc[0][0] = fmaf(wva.x, sv.x, acc[0][0]); acc[0][1] = fmaf(wva.x, sv.y, acc[0][1]);
      acc[0][2] = fmaf(wva.x, sv.z, acc[0][2]); acc[0][3] = fmaf(wva.x, sv.w, acc[0][3]);
      acc[1][0] = fmaf(wva.y, sv.x, acc[1][0]); acc[1][1] = fmaf(wva.y, sv.y, acc[1][1]);
      acc[1][2] = fmaf(wva.y, sv.z, acc[1][2]); acc[1][3] = fmaf(wva.y, sv.w, acc[1][3]);
      acc[2][0] = fmaf(wva.z, sv.x, acc[2][0]); acc[2][1] = fmaf(wva.z, sv.y, acc[2][1]);
      acc[2][2] = fmaf(wva.z, sv.z, acc[2][2]); acc[2][3] = fmaf(wva.z, sv.w, acc[2][3]);
      acc[3][0] = fmaf(wva.w, sv.x, acc[3][0]); acc[3][1] = fmaf(wva.w, sv.y, acc[3][1]);
      acc[3][2] = fmaf(wva.w, sv.z, acc[3][2]); acc[3][3] = fmaf(wva.w, sv.w, acc[3][3]);
      acc[4][0] = fmaf(wvb.x, sv.x, acc[4][0]); acc[4][1] = fmaf(wvb.x, sv.y, acc[4][1]);
      acc[4][2] = fmaf(wvb.x, sv.z, acc[4][2]); acc[4][3] = fmaf(wvb.x, sv.w, acc[4][3]);
      acc[5][0] = fmaf(wvb.y, sv.x, acc[5][0]); acc[5][1] = fmaf(wvb.y, sv.y, acc[5][1]);
      acc[5][2] = fmaf(wvb.y, sv.z, acc[5][2]); acc[5][3] = fmaf(wvb.y, sv.w, acc[5][3]);
      acc[6][0] = fmaf(wvb.z, sv.x, acc[6][0]); acc[6][1] = fmaf(wvb.z, sv.y, acc[6][1]);
      acc[6][2] = fmaf(wvb.z, sv.z, acc[6][2]); acc[6][3] = fmaf(wvb.z, sv.w, acc[6][3]);
      acc[7][0] = fmaf(wvb.w, sv.x, acc[7][0]); acc[7][1] = fmaf(wvb.w, sv.y, acc[7][1]);
      acc[7][2] = fmaf(wvb.w, sv.z, acc[7][2]); acc[7][3] = fmaf(wvb.w, sv.w, acc[7][3]);
    }
  }

  // write partials: part2[ks][b][o][h*64+w]
  float* pb = part2 + ((size_t)ks * BB * COUTC) * 4096;
#pragma unroll
  for (int i = 0; i < 8; i++) {
    float4 o;
    o.x = acc[i][0]; o.y = acc[i][1]; o.z = acc[i][2]; o.w = acc[i][3];
    *(float4*)&pb[((b * COUTC + co0 + i) * HH + h) * WW + w0] = o;
  }
}

// ---------------- K2r: sum 4 partials + bias -> out1
__global__ __launch_bounds__(256) void k2r(const float* __restrict__ part2,
                                           const float* __restrict__ dcn_b,
                                           float* __restrict__ out1) {
  int tid = blockIdx.x * 256 + threadIdx.x;
  if (tid >= BB * COUTC * HH * WW) return;
  int o = (tid >> 12) & 127;
  const int S = BB * COUTC * 4096;
  out1[tid] = part2[tid] + part2[tid + S] + part2[tid + 2 * S] + part2[tid + 3 * S] + dcn_b[o];
}

// ---------------- K3/K5: per-channel two-pass BN stats
__global__ __launch_bounds__(256) void k3_stats1(const float* __restrict__ out1,
                                                 const float* __restrict__ g, const float* __restrict__ bt,
                                                 float* __restrict__ scale, float* __restrict__ shift) {
  int c = blockIdx.x, t = threadIdx.x;
  __shared__ float r1[256];
  __shared__ float muS;
  float s = 0.f;
  for (int e = t; e < BB * HH * WW; e += 256) {
    int b = e >> 12, sp = e & 4095;
    s += out1[(b * COUTC + c) * 4096 + sp];
  }
  r1[t] = s;
  __syncthreads();
  for (int off = 128; off > 0; off >>= 1) {
    if (t < off) r1[t] += r1[t + off];
    __syncthreads();
  }
  if (t == 0) muS = r1[0] / 16384.f;
  __syncthreads();
  float mu = muS;
  __syncthreads();
  float s2 = 0.f;
  for (int e = t; e < BB * HH * WW; e += 256) {
    int b = e >> 12, sp = e & 4095;
    float d = out1[(b * COUTC + c) * 4096 + sp] - mu;
    s2 += d * d;
  }
  r1[t] = s2;
  __syncthreads();
  for (int off = 128; off > 0; off >>= 1) {
    if (t < off) r1[t] += r1[t + off];
    __syncthreads();
  }
  if (t == 0) {
    float var = r1[0] / 16384.f;
    float sc = g[c] * rsqrtf(var + 1e-5f);
    scale[c] = sc;
    shift[c] = bt[c] - mu * sc;
  }
}

__global__ __launch_bounds__(256) void k5_stats2(const float* __restrict__ out2,
                                                 const float* __restrict__ g, const float* __restrict__ bt,
                                                 float* __restrict__ scale, float* __restrict__ shift) {
  int c = blockIdx.x, t = threadIdx.x;
  __shared__ float r1[256];
  __shared__ float muS;
  float s = 0.f;
  for (int e = t; e < BB * OHH * OWW; e += 256) {
    int b = e >> 14, sp = e & 16383;
    s += out2[(b * COUTC + c) * 16384 + sp];
  }
  r1[t] = s;
  __syncthreads();
  for (int off = 128; off > 0; off >>= 1) {
    if (t < off) r1[t] += r1[t + off];
    __syncthreads();
  }
  if (t == 0) muS = r1[0] / 65536.f;
  __syncthreads();
  float mu = muS;
  __syncthreads();
  float s2 = 0.f;
  for (int e = t; e < BB * OHH * OWW; e += 256) {
    int b = e >> 14, sp = e & 16383;
    float d = out2[(b * COUTC + c) * 16384 + sp] - mu;
    s2 += d * d;
  }
  r1[t] = s2;
  __syncthreads();
  for (int off = 128; off > 0; off >>= 1) {
    if (t < off) r1[t] += r1[t + off];
    __syncthreads();
  }
  if (t == 0) {
    float var = r1[0] / 65536.f;
    float sc = g[c] * rsqrtf(var + 1e-5f);
    scale[c] = sc;
    shift[c] = bt[c] - mu * sc;
  }
}

// ---------------- K4f: bn1+relu fused transposed conv (tiled, parity-decomposed).
__global__ __launch_bounds__(256) void k4f(const float* __restrict__ out1,
                                           const float* __restrict__ s1,
                                           const float* __restrict__ sh1,
                                           const float* __restrict__ wt4,
                                           float* __restrict__ out2) {
  int oh = blockIdx.x, b = blockIdx.y;
  __shared__ __align__(16) float ys[2 * 128 * 64];  // exactly 64 KiB
  int t = threadIdx.x;
  int t0 = oh & 1;

#pragma unroll
  for (int ti = 0; ti < 2; ti++) {
    int tt = t0 + 2 * ti;
    int m = (oh + tt - 2) / 2;
    bool rowok = (m >= 0 && m < 64);
    for (int e = t; e < 2048; e += 256) {
      int i = e >> 4;
      float4 v = make_float4(0.f, 0.f, 0.f, 0.f);
      if (rowok) {
        float4 r = *(const float4*)&out1[((b * COUTC + i) * HH + m) * WW + (e & 15) * 4];
        float sc = s1[i], sh = sh1[i];
        v.x = fmaxf(fmaf(r.x, sc, sh), 0.f);
        v.y = fmaxf(fmaf(r.y, sc, sh), 0.f);
        v.z = fmaxf(fmaf(r.z, sc, sh), 0.f);
        v.w = fmaxf(fmaf(r.w, sc, sh), 0.f);
      }
      *(float4*)&ys[ti * 8192 + e * 4] = v;
    }
  }
  __syncthreads();

  int o = t >> 1, half = t & 1;
  int nb = half * 32;
  float acc[64];
#pragma unroll
  for (int j = 0; j < 64; j++) acc[j] = 0.f;

  const float* wb0 = wt4 + ((t0 * 128) * 128 + o) * 4;
  const float* wb1 = wt4 + (((t0 + 2) * 128) * 128 + o) * 4;

  for (int i = 0; i < 128; i++) {
#pragma unroll
    for (int ti = 0; ti < 2; ti++) {
      float4 wv = *(const float4*)((ti ? wb1 : wb0) + i * 512);
      float W0 = wv.x, W1 = wv.y, W2 = wv.z, W3 = wv.w;

      const float* yb = &ys[ti * 8192 + i * 64 + nb];
      float yv[34];
#pragma unroll
      for (int j4 = 0; j4 < 8; j4++) {
        float4 q4 = *(const float4*)(yb + 4 * j4);
        yv[1 + 4 * j4] = q4.x; yv[2 + 4 * j4] = q4.y;
        yv[3 + 4 * j4] = q4.z; yv[4 + 4 * j4] = q4.w;
      }
      yv[0]  = half ? yb[-1] : 0.f;
      yv[33] = half ? 0.f : yb[32];
#pragma unroll
      for (int u = 0; u < 32; u++) {
        acc[2 * u]     = fmaf(W0, yv[u],     fmaf(W2, yv[u + 1], acc[2 * u]));
        acc[2 * u + 1] = fmaf(W1, yv[u + 1], fmaf(W3, yv[u + 2], acc[2 * u + 1]));
      }
    }
  }

  float* op = out2 + ((b * COUTC + o) * OHH + oh) * OWW + half * 64;
#pragma unroll
  for (int j4 = 0; j4 < 16; j4++) {
    float4 v;
    v.x = acc[4 * j4]; v.y = acc[4 * j4 + 1]; v.z = acc[4 * j4 + 2]; v.w = acc[4 * j4 + 3];
    *(float4*)&op[4 * j4] = v;
  }
}

// ---------------- K6: bn2+relu apply (f32 out)
__global__ __launch_bounds__(256) void k6s(const float* __restrict__ out2,
                                           const float* __restrict__ scale2,
                                           const float* __restrict__ shift2,
                                           float* __restrict__ outp) {
  int tid = blockIdx.x * 256 + threadIdx.x;
  if (tid >= BB * COUTC * OHH * OWW) return;
  int c = (tid >> 14) & 127;
  outp[tid] = fmaxf(fmaf(out2[tid], scale2[c], shift2[c]), 0.f);
}

// ---------------- launch
extern "C" void kernel_launch(void* const* d_in, const int* in_sizes, int n_in,
                              void* d_out, int out_size, void* d_ws, size_t ws_size,
                              hipStream_t stream) {
  const float* x     = (const float*)d_in[0];
  const float* off_w = (const float*)d_in[1];
  const float* off_b = (const float*)d_in[2];
  const float* dcn_w = (const float*)d_in[3];
  const float* dcn_b = (const float*)d_in[4];
  const float* bn1_g = (const float*)d_in[5];
  const float* bn1_b = (const float*)d_in[6];
  const float* up_w  = (const float*)d_in[7];
  const float* bn2_g = (const float*)d_in[8];
  const float* bn2_b = (const float*)d_in[9];

  float* ws = (float*)d_ws;
  float* pyg  = ws;                              // 147456
  float* pxg  = pyg + BB * 9 * HH * WW;          // 147456
  float* mg   = pxg + BB * 9 * HH * WW;          // 147456
  float* out1 = mg + BB * 9 * HH * WW;           // 2097152
  float* scale1 = out1 + BB * COUTC * HH * WW;   // 128
  float* shift1 = scale1 + 128;                  // 128
  float* out2 = shift1 + 128;                    // 8388608
  float* scale2 = out2 + BB * COUTC * OHH * OWW; // 128
  float* shift2 = scale2 + 128;                  // 128
  float* w_t = shift2 + 128;                     // 294912
  float* wt4 = w_t + COUTC * CINC * 9;           // 262144
  float* part2 = wt4 + 4 * COUTC * COUTC * 4;    // 4 * 2097152
  // k1 partials overlaid on out2 region (k1p/k1r complete before k4f writes out2)
  float* part = out2;

  const int N4 = BB * COUTC * OHH * OWW;  // 8388608
  const int N2 = BB * COUTC * HH * WW;    // 2097152
  const int N1 = BB * 27 * HH * WW;       // 442368

  k0t<<<(COUTC * CINC * 9 + 255) / 256, 256, 0, stream>>>(dcn_w, w_t);
  k0u<<<(4 * COUTC * COUTC * 4 + 255) / 256, 256, 0, stream>>>(up_w, wt4);
  k1p<<<dim3(4, 64, 4), 256, 0, stream>>>(x, off_w, part);
  k1r<<<(N1 + 255) / 256, 256, 0, stream>>>(part, off_b, pyg, pxg, mg);
  k2p<<<dim3(4, 64, 4), 256, 0, stream>>>(x, w_t, pyg, pxg, mg, part2);
  k2r<<<(N2 + 255) / 256, 256, 0, stream>>>(part2, dcn_b, out1);
  k3_stats1<<<COUTC, 256, 0, stream>>>(out1, bn1_g, bn1_b, scale1, shift1);
  k4f<<<dim3(128, 4), 256, 0, stream>>>(out1, scale1, shift1, wt4, out2);
  k5_stats2<<<COUTC, 256, 0, stream>>>(out2, bn2_g, bn2_b, scale2, shift2);
  k6s<<<(N4 + 255) / 256, 256, 0, stream>>>(out2, scale2, shift2, (float*)d_out);
}

// Round 10
// 742.552 us; speedup vs baseline: 1.0436x; 1.0436x over previous
//
#include <hip/hip_runtime.h>
#include <math.h>

// Problem constants
#define BB 4
#define CINC 256
#define COUTC 128
#define HH 64
#define WW 64
#define OHH 128
#define OWW 128

// ---------------- K0t: transpose dcn_w [o][c][q] -> w_t[(c*9+q)][o]
__global__ __launch_bounds__(256) void k0t(const float* __restrict__ dcn_w, float* __restrict__ w_t) {
  int tid = blockIdx.x * 256 + threadIdx.x;
  if (tid >= COUTC * CINC * 9) return;
  int ck = tid >> 7;
  int o = tid & 127;
  w_t[tid] = dcn_w[o * (CINC * 9) + ck];
}

// ---------------- K0u: transpose up_w -> wt4[tt][i][o][s]
__global__ __launch_bounds__(256) void k0u(const float* __restrict__ up_w, float* __restrict__ wt4) {
  int tid = blockIdx.x * 256 + threadIdx.x;
  if (tid >= 4 * COUTC * COUTC * 4) return;
  int s = tid & 3;
  int o = (tid >> 2) & 127;
  int i = (tid >> 9) & 127;
  int tt = tid >> 16;
  wt4[tid] = up_w[((i * COUTC + o) * 4 + (3 - tt)) * 4 + (3 - s)];
}

// ---------------- K1p: offset conv split-K partials. grid (4,64,4)=(cc,h,b), 256 thr.
__global__ __launch_bounds__(256) void k1p(const float* __restrict__ x,
                                           const float* __restrict__ off_w,
                                           float* __restrict__ part) {
  int cc = blockIdx.x, h = blockIdx.y, b = blockIdx.z;
  __shared__ float xs[3 * 32 * 66];
  int t = threadIdx.x;
  int tw = t & 63;
  int tg = __builtin_amdgcn_readfirstlane(t >> 6);

  float acc[7];
#pragma unroll
  for (int j = 0; j < 7; j++) acc[j] = 0.f;

  for (int cs = 0; cs < 2; cs++) {
    int c0 = cc * 64 + cs * 32;
    __syncthreads();
    for (int e = t; e < 3 * 32 * 66; e += 256) {
      int r = e / (32 * 66);
      int rem = e - r * (32 * 66);
      int c = rem / 66;
      int wi = rem - c * 66;
      int row = h - 1 + r;
      int col = wi - 1;
      float v = 0.f;
      if (row >= 0 && row < HH && col >= 0 && col < WW)
        v = x[((b * CINC + c0 + c) * HH + row) * WW + col];
      xs[(r * 32 + c) * 66 + wi] = v;
    }
    __syncthreads();
    for (int c = 0; c < 32; c++) {
      float xv[9];
#pragma unroll
      for (int r = 0; r < 3; r++)
#pragma unroll
        for (int dx = 0; dx < 3; dx++)
          xv[r * 3 + dx] = xs[(r * 32 + c) * 66 + tw + dx];
#pragma unroll
      for (int j = 0; j < 7; j++) {
        int oc = tg + 4 * j;
        if (oc < 27) {
          const float* wp = off_w + (oc * CINC + c0 + c) * 9;  // uniform -> s_load
#pragma unroll
          for (int q = 0; q < 9; q++) acc[j] = fmaf(xv[q], wp[q], acc[j]);
        }
      }
    }
  }

#pragma unroll
  for (int j = 0; j < 7; j++) {
    int oc = tg + 4 * j;
    if (oc < 27)
      part[((cc * BB + b) * 27 + oc) * 4096 + h * 64 + tw] = acc[j];
  }
}

// ---------------- K1r: reduce 4 partials + bias -> py/px/m
__global__ __launch_bounds__(256) void k1r(const float* __restrict__ part,
                                           const float* __restrict__ off_b,
                                           float* __restrict__ pyg,
                                           float* __restrict__ pxg,
                                           float* __restrict__ mg) {
  int tid = blockIdx.x * 256 + threadIdx.x;
  if (tid >= BB * 27 * HH * WW) return;
  int w = tid & 63;
  int h = (tid >> 6) & 63;
  int oc = (tid >> 12) % 27;
  int b = tid / (27 * 4096);
  int sp = tid & 4095;

  float v = off_b[oc];
#pragma unroll
  for (int cc = 0; cc < 4; cc++)
    v += part[((cc * BB + b) * 27 + oc) * 4096 + sp];

  int k = oc % 9;
  int gi = ((b * 9 + k) * HH + h) * WW + w;
  if (oc < 9) {
    pyg[gi] = v + (float)(oc / 3) - 1.f + (float)h;
  } else if (oc < 18) {
    pxg[gi] = v + (float)((oc - 9) % 3) - 1.f + (float)w;
  } else {
    mg[gi] = 1.f / (1.f + expf(-v));
  }
}

// ---------------- K2p: deformable conv, split-K(4) GEMM. grid (4,64,4)=(ks,h,b).
// Block: 64 px (row h) x 128 cout x 64 input channels (16 chunks of 4 ch = 36 ck).
// Per-thread bilinear descriptors (weights premasked*m, offsets packed u16) hoisted
// out of the chunk loop: thread t's 9 (ck,px) slots repeat every chunk.
__global__ __launch_bounds__(256) void k2p(const float* __restrict__ x,
                                           const float* __restrict__ w_t,
                                           const float* __restrict__ pyg,
                                           const float* __restrict__ pxg,
                                           const float* __restrict__ mg,
                                           float* __restrict__ part2) {
  int ks = blockIdx.x, h = blockIdx.y, b = blockIdx.z;
  __shared__ __align__(16) float scol[36 * 64];   // (4ch x 9k) x 64 px
  __shared__ __align__(16) float wlS[36 * 128];   // 36 ck x 128 cout
  int t = threadIdx.x;

  // ---- precompute 9 sample descriptors (fixed across chunks) ----
  float w00[9], w01[9], w10[9], w11[9];
  int offA[9], offB[9];  // packed u16 pairs: cdiv*4096 + spatial (<16384)
#pragma unroll
  for (int j = 0; j < 9; j++) {
    int e = t + 256 * j;       // 0..2303 = ck*64 + wl
    int ck = e >> 6;           // 0..35
    int wl = e & 63;
    int cdiv = ck / 9;         // 0..3 (channel within chunk)
    int k = ck - 9 * cdiv;     // kernel tap
    int gi = ((b * 9 + k) * HH + h) * WW + wl;
    float py = pyg[gi], px = pxg[gi], m = mg[gi];
    float y0f = floorf(py), x0f = floorf(px);
    float wy = py - y0f, wx = px - x0f;
    int y0 = (int)y0f, x0 = (int)x0f;
    bool vy0 = (unsigned)y0 < (unsigned)HH, vy1 = (unsigned)(y0 + 1) < (unsigned)HH;
    bool vx0 = (unsigned)x0 < (unsigned)WW, vx1 = (unsigned)(x0 + 1) < (unsigned)WW;
    int y0c = min(max(y0, 0), HH - 1), y1c = min(max(y0 + 1, 0), HH - 1);
    int x0c = min(max(x0, 0), WW - 1), x1c = min(max(x0 + 1, 0), WW - 1);
    w00[j] = (vy0 && vx0) ? (1.f - wy) * (1.f - wx) * m : 0.f;
    w01[j] = (vy0 && vx1) ? (1.f - wy) * wx * m : 0.f;
    w10[j] = (vy1 && vx0) ? wy * (1.f - wx) * m : 0.f;
    w11[j] = (vy1 && vx1) ? wy * wx * m : 0.f;
    int cb = cdiv * (HH * WW);
    offA[j] = (cb + y0c * WW + x0c) | ((cb + y0c * WW + x1c) << 16);
    offB[j] = (cb + y1c * WW + x0c) | ((cb + y1c * WW + x1c) << 16);
  }

  float acc[8][4];
#pragma unroll
  for (int i = 0; i < 8; i++)
#pragma unroll
    for (int j = 0; j < 4; j++) acc[i][j] = 0.f;

  int co0 = (t >> 4) * 8;   // 0..120 (16 lanes share)
  int w0 = (t & 15) * 4;    // 0..60
  const float* xpb = x + b * CINC * HH * WW;

  for (int cs = 0; cs < 16; cs++) {
    int c0 = ks * 64 + cs * 4;  // uniform
    __syncthreads();
    // weights: 4608 floats = 2304 float2, 9 per thread (contiguous, coalesced)
    const float2* wsrc = (const float2*)(w_t + c0 * 9 * 128);
    float2* wdst = (float2*)wlS;
#pragma unroll
    for (int j = 0; j < 9; j++) wdst[t + 256 * j] = wsrc[t + 256 * j];
    // gather: 4 clamped loads x premasked weights per sample
    const float* xp = xpb + c0 * (HH * WW);  // uniform base
#pragma unroll
    for (int j = 0; j < 9; j++) {
      float v = w00[j] * xp[offA[j] & 0xffff]
              + w01[j] * xp[offA[j] >> 16]
              + w10[j] * xp[offB[j] & 0xffff]
              + w11[j] * xp[offB[j] >> 16];
      scol[t + 256 * j] = v;
    }
    __syncthreads();
    // compute: 36 ck x (8 cout x 4 px), both operands from LDS
#pragma unroll 4
    for (int ck = 0; ck < 36; ck++) {
      float4 sv = *(const float4*)&scol[ck * 64 + w0];
      float4 wva = *(const float4*)&wlS[ck * 128 + co0];
      float4 wvb = *(const float4*)&wlS[ck * 128 + co0 + 4];
      acc[0][0] = fmaf(wva.x, sv.x, acc[0][0]); acc[0][1] = fmaf(wva.x, sv.y, acc[0][1]);
      acc[0][2] = fmaf(wva.x, sv.z, acc[0][2]); acc[0][3] = fmaf(wva.x, sv.w, acc[0][3]);
      acc[1][0] = fmaf(wva.y, sv.x, acc[1][0]); acc[1][1] = fmaf(wva.y, sv.y, acc[1][1]);
      acc[1][2] = fmaf(wva.y, sv.z, acc[1][2]); acc[1][3] = fmaf(wva.y, sv.w, acc[1][3]);
      acc[2][0] = fmaf(wva.z, sv.x, acc[2][0]); acc[2][1] = fmaf(wva.z, sv.y, acc[2][1]);
      acc[2][2] = fmaf(wva.z, sv.z, acc[2][2]); acc[2][3] = fmaf(wva.z, sv.w, acc[2][3]);
      acc[3][0] = fmaf(wva.w, sv.x, acc[3][0]); acc[3][1] = fmaf(wva.w, sv.y, acc[3][1]);
      acc[3][2] = fmaf(wva.w, sv.z, acc[3][2]); acc[3][3] = fmaf(wva.w, sv.w, acc[3][3]);
      acc[4][0] = fmaf(wvb.x, sv.x, acc[4][0]); acc[4][1] = fmaf(wvb.x, sv.y, acc[4][1]);
      acc[4][2] = fmaf(wvb.x, sv.z, acc[4][2]); acc[4][3] = fmaf(wvb.x, sv.w, acc[4][3]);
      acc[5][0] = fmaf(wvb.y, sv.x, acc[5][0]); acc[5][1] = fmaf(wvb.y, sv.y, acc[5][1]);
      acc[5][2] = fmaf(wvb.y, sv.z, acc[5][2]); acc[5][3] = fmaf(wvb.y, sv.w, acc[5][3]);
      acc[6][0] = fmaf(wvb.z, sv.x, acc[6][0]); acc[6][1] = fmaf(wvb.z, sv.y, acc[6][1]);
      acc[6][2] = fmaf(wvb.z, sv.z, acc[6][2]); acc[6][3] = fmaf(wvb.z, sv.w, acc[6][3]);
      acc[7][0] = fmaf(wvb.w, sv.x, acc[7][0]); acc[7][1] = fmaf(wvb.w, sv.y, acc[7][1]);
      acc[7][2] = fmaf(wvb.w, sv.z, acc[7][2]); acc[7][3] = fmaf(wvb.w, sv.w, acc[7][3]);
    }
  }

  // write partials: part2[ks][b][o][h*64+w]
  float* pb = part2 + ((size_t)ks * BB * COUTC) * 4096;
#pragma unroll
  for (int i = 0; i < 8; i++) {
    float4 o;
    o.x = acc[i][0]; o.y = acc[i][1]; o.z = acc[i][2]; o.w = acc[i][3];
    *(float4*)&pb[((b * COUTC + co0 + i) * HH + h) * WW + w0] = o;
  }
}

// ---------------- K2r: sum 4 partials + bias -> out1
__global__ __launch_bounds__(256) void k2r(const float* __restrict__ part2,
                                           const float* __restrict__ dcn_b,
                                           float* __restrict__ out1) {
  int tid = blockIdx.x * 256 + threadIdx.x;
  if (tid >= BB * COUTC * HH * WW) return;
  int o = (tid >> 12) & 127;
  const int S = BB * COUTC * 4096;
  out1[tid] = part2[tid] + part2[tid + S] + part2[tid + 2 * S] + part2[tid + 3 * S] + dcn_b[o];
}

// ---------------- K3/K5: per-channel two-pass BN stats
__global__ __launch_bounds__(256) void k3_stats1(const float* __restrict__ out1,
                                                 const float* __restrict__ g, const float* __restrict__ bt,
                                                 float* __restrict__ scale, float* __restrict__ shift) {
  int c = blockIdx.x, t = threadIdx.x;
  __shared__ float r1[256];
  __shared__ float muS;
  float s = 0.f;
  for (int e = t; e < BB * HH * WW; e += 256) {
    int b = e >> 12, sp = e & 4095;
    s += out1[(b * COUTC + c) * 4096 + sp];
  }
  r1[t] = s;
  __syncthreads();
  for (int off = 128; off > 0; off >>= 1) {
    if (t < off) r1[t] += r1[t + off];
    __syncthreads();
  }
  if (t == 0) muS = r1[0] / 16384.f;
  __syncthreads();
  float mu = muS;
  __syncthreads();
  float s2 = 0.f;
  for (int e = t; e < BB * HH * WW; e += 256) {
    int b = e >> 12, sp = e & 4095;
    float d = out1[(b * COUTC + c) * 4096 + sp] - mu;
    s2 += d * d;
  }
  r1[t] = s2;
  __syncthreads();
  for (int off = 128; off > 0; off >>= 1) {
    if (t < off) r1[t] += r1[t + off];
    __syncthreads();
  }
  if (t == 0) {
    float var = r1[0] / 16384.f;
    float sc = g[c] * rsqrtf(var + 1e-5f);
    scale[c] = sc;
    shift[c] = bt[c] - mu * sc;
  }
}

__global__ __launch_bounds__(256) void k5_stats2(const float* __restrict__ out2,
                                                 const float* __restrict__ g, const float* __restrict__ bt,
                                                 float* __restrict__ scale, float* __restrict__ shift) {
  int c = blockIdx.x, t = threadIdx.x;
  __shared__ float r1[256];
  __shared__ float muS;
  float s = 0.f;
  for (int e = t; e < BB * OHH * OWW; e += 256) {
    int b = e >> 14, sp = e & 16383;
    s += out2[(b * COUTC + c) * 16384 + sp];
  }
  r1[t] = s;
  __syncthreads();
  for (int off = 128; off > 0; off >>= 1) {
    if (t < off) r1[t] += r1[t + off];
    __syncthreads();
  }
  if (t == 0) muS = r1[0] / 65536.f;
  __syncthreads();
  float mu = muS;
  __syncthreads();
  float s2 = 0.f;
  for (int e = t; e < BB * OHH * OWW; e += 256) {
    int b = e >> 14, sp = e & 16383;
    float d = out2[(b * COUTC + c) * 16384 + sp] - mu;
    s2 += d * d;
  }
  r1[t] = s2;
  __syncthreads();
  for (int off = 128; off > 0; off >>= 1) {
    if (t < off) r1[t] += r1[t + off];
    __syncthreads();
  }
  if (t == 0) {
    float var = r1[0] / 65536.f;
    float sc = g[c] * rsqrtf(var + 1e-5f);
    scale[c] = sc;
    shift[c] = bt[c] - mu * sc;
  }
}

// ---------------- K4f: bn1+relu fused transposed conv (tiled, parity-decomposed).
__global__ __launch_bounds__(256) void k4f(const float* __restrict__ out1,
                                           const float* __restrict__ s1,
                                           const float* __restrict__ sh1,
                                           const float* __restrict__ wt4,
                                           float* __restrict__ out2) {
  int oh = blockIdx.x, b = blockIdx.y;
  __shared__ __align__(16) float ys[2 * 128 * 64];  // exactly 64 KiB
  int t = threadIdx.x;
  int t0 = oh & 1;

#pragma unroll
  for (int ti = 0; ti < 2; ti++) {
    int tt = t0 + 2 * ti;
    int m = (oh + tt - 2) / 2;
    bool rowok = (m >= 0 && m < 64);
    for (int e = t; e < 2048; e += 256) {
      int i = e >> 4;
      float4 v = make_float4(0.f, 0.f, 0.f, 0.f);
      if (rowok) {
        float4 r = *(const float4*)&out1[((b * COUTC + i) * HH + m) * WW + (e & 15) * 4];
        float sc = s1[i], sh = sh1[i];
        v.x = fmaxf(fmaf(r.x, sc, sh), 0.f);
        v.y = fmaxf(fmaf(r.y, sc, sh), 0.f);
        v.z = fmaxf(fmaf(r.z, sc, sh), 0.f);
        v.w = fmaxf(fmaf(r.w, sc, sh), 0.f);
      }
      *(float4*)&ys[ti * 8192 + e * 4] = v;
    }
  }
  __syncthreads();

  int o = t >> 1, half = t & 1;
  int nb = half * 32;
  float acc[64];
#pragma unroll
  for (int j = 0; j < 64; j++) acc[j] = 0.f;

  const float* wb0 = wt4 + ((t0 * 128) * 128 + o) * 4;
  const float* wb1 = wt4 + (((t0 + 2) * 128) * 128 + o) * 4;

  for (int i = 0; i < 128; i++) {
#pragma unroll
    for (int ti = 0; ti < 2; ti++) {
      float4 wv = *(const float4*)((ti ? wb1 : wb0) + i * 512);
      float W0 = wv.x, W1 = wv.y, W2 = wv.z, W3 = wv.w;

      const float* yb = &ys[ti * 8192 + i * 64 + nb];
      float yv[34];
#pragma unroll
      for (int j4 = 0; j4 < 8; j4++) {
        float4 q4 = *(const float4*)(yb + 4 * j4);
        yv[1 + 4 * j4] = q4.x; yv[2 + 4 * j4] = q4.y;
        yv[3 + 4 * j4] = q4.z; yv[4 + 4 * j4] = q4.w;
      }
      yv[0]  = half ? yb[-1] : 0.f;
      yv[33] = half ? 0.f : yb[32];
#pragma unroll
      for (int u = 0; u < 32; u++) {
        acc[2 * u]     = fmaf(W0, yv[u],     fmaf(W2, yv[u + 1], acc[2 * u]));
        acc[2 * u + 1] = fmaf(W1, yv[u + 1], fmaf(W3, yv[u + 2], acc[2 * u + 1]));
      }
    }
  }

  float* op = out2 + ((b * COUTC + o) * OHH + oh) * OWW + half * 64;
#pragma unroll
  for (int j4 = 0; j4 < 16; j4++) {
    float4 v;
    v.x = acc[4 * j4]; v.y = acc[4 * j4 + 1]; v.z = acc[4 * j4 + 2]; v.w = acc[4 * j4 + 3];
    *(float4*)&op[4 * j4] = v;
  }
}

// ---------------- K6: bn2+relu apply (f32 out)
__global__ __launch_bounds__(256) void k6s(const float* __restrict__ out2,
                                           const float* __restrict__ scale2,
                                           const float* __restrict__ shift2,
                                           float* __restrict__ outp) {
  int tid = blockIdx.x * 256 + threadIdx.x;
  if (tid >= BB * COUTC * OHH * OWW) return;
  int c = (tid >> 14) & 127;
  outp[tid] = fmaxf(fmaf(out2[tid], scale2[c], shift2[c]), 0.f);
}

// ---------------- launch
extern "C" void kernel_launch(void* const* d_in, const int* in_sizes, int n_in,
                              void* d_out, int out_size, void* d_ws, size_t ws_size,
                              hipStream_t stream) {
  const float* x     = (const float*)d_in[0];
  const float* off_w = (const float*)d_in[1];
  const float* off_b = (const float*)d_in[2];
  const float* dcn_w = (const float*)d_in[3];
  const float* dcn_b = (const float*)d_in[4];
  const float* bn1_g = (const float*)d_in[5];
  const float* bn1_b = (const float*)d_in[6];
  const float* up_w  = (const float*)d_in[7];
  const float* bn2_g = (const float*)d_in[8];
  const float* bn2_b = (const float*)d_in[9];

  float* ws = (float*)d_ws;
  float* pyg  = ws;                              // 147456
  float* pxg  = pyg + BB * 9 * HH * WW;          // 147456
  float* mg   = pxg + BB * 9 * HH * WW;          // 147456
  float* out1 = mg + BB * 9 * HH * WW;           // 2097152
  float* scale1 = out1 + BB * COUTC * HH * WW;   // 128
  float* shift1 = scale1 + 128;                  // 128
  float* out2 = shift1 + 128;                    // 8388608
  float* scale2 = out2 + BB * COUTC * OHH * OWW; // 128
  float* shift2 = scale2 + 128;                  // 128
  float* w_t = shift2 + 128;                     // 294912
  float* wt4 = w_t + COUTC * CINC * 9;           // 262144
  float* part2 = wt4 + 4 * COUTC * COUTC * 4;    // 4 * 2097152
  // k1 partials overlaid on out2 region (k1p/k1r complete before k4f writes out2)
  float* part = out2;

  const int N4 = BB * COUTC * OHH * OWW;  // 8388608
  const int N2 = BB * COUTC * HH * WW;    // 2097152
  const int N1 = BB * 27 * HH * WW;       // 442368

  k0t<<<(COUTC * CINC * 9 + 255) / 256, 256, 0, stream>>>(dcn_w, w_t);
  k0u<<<(4 * COUTC * COUTC * 4 + 255) / 256, 256, 0, stream>>>(up_w, wt4);
  k1p<<<dim3(4, 64, 4), 256, 0, stream>>>(x, off_w, part);
  k1r<<<(N1 + 255) / 256, 256, 0, stream>>>(part, off_b, pyg, pxg, mg);
  k2p<<<dim3(4, 64, 4), 256, 0, stream>>>(x, w_t, pyg, pxg, mg, part2);
  k2r<<<(N2 + 255) / 256, 256, 0, stream>>>(part2, dcn_b, out1);
  k3_stats1<<<COUTC, 256, 0, stream>>>(out1, bn1_g, bn1_b, scale1, shift1);
  k4f<<<dim3(128, 4), 256, 0, stream>>>(out1, scale1, shift1, wt4, out2);
  k5_stats2<<<COUTC, 256, 0, stream>>>(out2, bn2_g, bn2_b, scale2, shift2);
  k6s<<<(N4 + 255) / 256, 256, 0, stream>>>(out2, scale2, shift2, (float*)d_out);
}

// Round 11
// 643.503 us; speedup vs baseline: 1.2042x; 1.1539x over previous
//
#include <hip/hip_runtime.h>
#include <math.h>

// Problem constants
#define BB 4
#define CINC 256
#define COUTC 128
#define HH 64
#define WW 64
#define OHH 128
#define OWW 128

// ---------------- K0t: transpose dcn_w [o][c][q] -> w_t[(c*9+q)][o]
__global__ __launch_bounds__(256) void k0t(const float* __restrict__ dcn_w, float* __restrict__ w_t) {
  int tid = blockIdx.x * 256 + threadIdx.x;
  if (tid >= COUTC * CINC * 9) return;
  int ck = tid >> 7;
  int o = tid & 127;
  w_t[tid] = dcn_w[o * (CINC * 9) + ck];
}

// ---------------- K0u: transpose up_w -> wt4[tt][i][o][s]
__global__ __launch_bounds__(256) void k0u(const float* __restrict__ up_w, float* __restrict__ wt4) {
  int tid = blockIdx.x * 256 + threadIdx.x;
  if (tid >= 4 * COUTC * COUTC * 4) return;
  int s = tid & 3;
  int o = (tid >> 2) & 127;
  int i = (tid >> 9) & 127;
  int tt = tid >> 16;
  wt4[tid] = up_w[((i * COUTC + o) * 4 + (3 - tt)) * 4 + (3 - s)];
}

// ---------------- K1p: offset conv split-K partials. grid (4,64,4)=(cc,h,b), 256 thr.
__global__ __launch_bounds__(256) void k1p(const float* __restrict__ x,
                                           const float* __restrict__ off_w,
                                           float* __restrict__ part) {
  int cc = blockIdx.x, h = blockIdx.y, b = blockIdx.z;
  __shared__ float xs[3 * 32 * 66];
  int t = threadIdx.x;
  int tw = t & 63;
  int tg = __builtin_amdgcn_readfirstlane(t >> 6);

  float acc[7];
#pragma unroll
  for (int j = 0; j < 7; j++) acc[j] = 0.f;

  for (int cs = 0; cs < 2; cs++) {
    int c0 = cc * 64 + cs * 32;
    __syncthreads();
    for (int e = t; e < 3 * 32 * 66; e += 256) {
      int r = e / (32 * 66);
      int rem = e - r * (32 * 66);
      int c = rem / 66;
      int wi = rem - c * 66;
      int row = h - 1 + r;
      int col = wi - 1;
      float v = 0.f;
      if (row >= 0 && row < HH && col >= 0 && col < WW)
        v = x[((b * CINC + c0 + c) * HH + row) * WW + col];
      xs[(r * 32 + c) * 66 + wi] = v;
    }
    __syncthreads();
    for (int c = 0; c < 32; c++) {
      float xv[9];
#pragma unroll
      for (int r = 0; r < 3; r++)
#pragma unroll
        for (int dx = 0; dx < 3; dx++)
          xv[r * 3 + dx] = xs[(r * 32 + c) * 66 + tw + dx];
#pragma unroll
      for (int j = 0; j < 7; j++) {
        int oc = tg + 4 * j;
        if (oc < 27) {
          const float* wp = off_w + (oc * CINC + c0 + c) * 9;  // uniform -> s_load
#pragma unroll
          for (int q = 0; q < 9; q++) acc[j] = fmaf(xv[q], wp[q], acc[j]);
        }
      }
    }
  }

#pragma unroll
  for (int j = 0; j < 7; j++) {
    int oc = tg + 4 * j;
    if (oc < 27)
      part[((cc * BB + b) * 27 + oc) * 4096 + h * 64 + tw] = acc[j];
  }
}

// ---------------- K1r: reduce 4 partials + bias -> py/px/m
__global__ __launch_bounds__(256) void k1r(const float* __restrict__ part,
                                           const float* __restrict__ off_b,
                                           float* __restrict__ pyg,
                                           float* __restrict__ pxg,
                                           float* __restrict__ mg) {
  int tid = blockIdx.x * 256 + threadIdx.x;
  if (tid >= BB * 27 * HH * WW) return;
  int w = tid & 63;
  int h = (tid >> 6) & 63;
  int oc = (tid >> 12) % 27;
  int b = tid / (27 * 4096);
  int sp = tid & 4095;

  float v = off_b[oc];
#pragma unroll
  for (int cc = 0; cc < 4; cc++)
    v += part[((cc * BB + b) * 27 + oc) * 4096 + sp];

  int k = oc % 9;
  int gi = ((b * 9 + k) * HH + h) * WW + w;
  if (oc < 9) {
    pyg[gi] = v + (float)(oc / 3) - 1.f + (float)h;
  } else if (oc < 18) {
    pxg[gi] = v + (float)((oc - 9) % 3) - 1.f + (float)w;
  } else {
    mg[gi] = 1.f / (1.f + expf(-v));
  }
}

// ---------------- K2p: deformable conv, split-K(4) GEMM, software-pipelined.
// grid (4,64,4)=(ks,h,b). Block: 64 px x 128 cout x 64 ch (16 chunks of 4ch=36ck).
// Chunk cs+1's gather (36 dword) + weight (9 float2) loads are issued right after
// chunk cs's LDS commit and consumed after the ~3.6k-cycle compute -> latency hidden.
__global__ __launch_bounds__(256) void k2p(const float* __restrict__ x,
                                           const float* __restrict__ w_t,
                                           const float* __restrict__ pyg,
                                           const float* __restrict__ pxg,
                                           const float* __restrict__ mg,
                                           float* __restrict__ part2) {
  int ks = blockIdx.x, h = blockIdx.y, b = blockIdx.z;
  __shared__ __align__(16) float scol[36 * 64];   // (4ch x 9k) x 64 px
  __shared__ __align__(16) float wlS[36 * 128];   // 36 ck x 128 cout
  int t = threadIdx.x;

  // ---- precompute 9 sample descriptors (fixed across chunks) ----
  float w00[9], w01[9], w10[9], w11[9];
  int offA[9], offB[9];  // packed u16 pairs: cdiv*4096 + spatial (<16384)
#pragma unroll
  for (int j = 0; j < 9; j++) {
    int e = t + 256 * j;       // 0..2303 = ck*64 + wl
    int ck = e >> 6;           // 0..35
    int wl = e & 63;
    int cdiv = ck / 9;         // 0..3 (channel within chunk)
    int k = ck - 9 * cdiv;     // kernel tap
    int gi = ((b * 9 + k) * HH + h) * WW + wl;
    float py = pyg[gi], px = pxg[gi], m = mg[gi];
    float y0f = floorf(py), x0f = floorf(px);
    float wy = py - y0f, wx = px - x0f;
    int y0 = (int)y0f, x0 = (int)x0f;
    bool vy0 = (unsigned)y0 < (unsigned)HH, vy1 = (unsigned)(y0 + 1) < (unsigned)HH;
    bool vx0 = (unsigned)x0 < (unsigned)WW, vx1 = (unsigned)(x0 + 1) < (unsigned)WW;
    int y0c = min(max(y0, 0), HH - 1), y1c = min(max(y0 + 1, 0), HH - 1);
    int x0c = min(max(x0, 0), WW - 1), x1c = min(max(x0 + 1, 0), WW - 1);
    w00[j] = (vy0 && vx0) ? (1.f - wy) * (1.f - wx) * m : 0.f;
    w01[j] = (vy0 && vx1) ? (1.f - wy) * wx * m : 0.f;
    w10[j] = (vy1 && vx0) ? wy * (1.f - wx) * m : 0.f;
    w11[j] = (vy1 && vx1) ? wy * wx * m : 0.f;
    int cb = cdiv * (HH * WW);
    offA[j] = (cb + y0c * WW + x0c) | ((cb + y0c * WW + x1c) << 16);
    offB[j] = (cb + y1c * WW + x0c) | ((cb + y1c * WW + x1c) << 16);
  }

  float acc[8][4];
#pragma unroll
  for (int i = 0; i < 8; i++)
#pragma unroll
    for (int j = 0; j < 4; j++) acc[i][j] = 0.f;

  int co0 = (t >> 4) * 8;   // 0..120 (16 lanes share)
  int w0 = (t & 15) * 4;    // 0..60
  const float* xpb = x + b * CINC * HH * WW;

  // ---- prefetch chunk 0 ----
  float rx[36];
  float2 rw[9];
  {
    int c0 = ks * 64;
    const float2* wsrc = (const float2*)(w_t + c0 * 9 * 128);
#pragma unroll
    for (int j = 0; j < 9; j++) rw[j] = wsrc[t + 256 * j];
    const float* xp = xpb + c0 * (HH * WW);
#pragma unroll
    for (int j = 0; j < 9; j++) {
      rx[4 * j + 0] = xp[offA[j] & 0xffff];
      rx[4 * j + 1] = xp[offA[j] >> 16];
      rx[4 * j + 2] = xp[offB[j] & 0xffff];
      rx[4 * j + 3] = xp[offB[j] >> 16];
    }
  }

  for (int cs = 0; cs < 16; cs++) {
    __syncthreads();  // previous compute done reading LDS
    // combine prefetched gather -> scol; commit prefetched weights -> wlS
#pragma unroll
    for (int j = 0; j < 9; j++) {
      float v = w00[j] * rx[4 * j + 0] + w01[j] * rx[4 * j + 1] +
                w10[j] * rx[4 * j + 2] + w11[j] * rx[4 * j + 3];
      scol[t + 256 * j] = v;
    }
    float2* wdst = (float2*)wlS;
#pragma unroll
    for (int j = 0; j < 9; j++) wdst[t + 256 * j] = rw[j];
    // issue next chunk's loads (land during compute below)
    if (cs < 15) {
      int c0 = ks * 64 + (cs + 1) * 4;
      const float2* wsrc = (const float2*)(w_t + c0 * 9 * 128);
#pragma unroll
      for (int j = 0; j < 9; j++) rw[j] = wsrc[t + 256 * j];
      const float* xp = xpb + c0 * (HH * WW);
#pragma unroll
      for (int j = 0; j < 9; j++) {
        rx[4 * j + 0] = xp[offA[j] & 0xffff];
        rx[4 * j + 1] = xp[offA[j] >> 16];
        rx[4 * j + 2] = xp[offB[j] & 0xffff];
        rx[4 * j + 3] = xp[offB[j] >> 16];
      }
    }
    __syncthreads();  // LDS ready (lgkm only)
    // compute: 36 ck x (8 cout x 4 px), both operands from LDS
#pragma unroll 4
    for (int ck = 0; ck < 36; ck++) {
      float4 sv = *(const float4*)&scol[ck * 64 + w0];
      float4 wva = *(const float4*)&wlS[ck * 128 + co0];
      float4 wvb = *(const float4*)&wlS[ck * 128 + co0 + 4];
      acc[0][0] = fmaf(wva.x, sv.x, acc[0][0]); acc[0][1] = fmaf(wva.x, sv.y, acc[0][1]);
      acc[0][2] = fmaf(wva.x, sv.z, acc[0][2]); acc[0][3] = fmaf(wva.x, sv.w, acc[0][3]);
      acc[1][0] = fmaf(wva.y, sv.x, acc[1][0]); acc[1][1] = fmaf(wva.y, sv.y, acc[1][1]);
      acc[1][2] = fmaf(wva.y, sv.z, acc[1][2]); acc[1][3] = fmaf(wva.y, sv.w, acc[1][3]);
      acc[2][0] = fmaf(wva.z, sv.x, acc[2][0]); acc[2][1] = fmaf(wva.z, sv.y, acc[2][1]);
      acc[2][2] = fmaf(wva.z, sv.z, acc[2][2]); acc[2][3] = fmaf(wva.z, sv.w, acc[2][3]);
      acc[3][0] = fmaf(wva.w, sv.x, acc[3][0]); acc[3][1] = fmaf(wva.w, sv.y, acc[3][1]);
      acc[3][2] = fmaf(wva.w, sv.z, acc[3][2]); acc[3][3] = fmaf(wva.w, sv.w, acc[3][3]);
      acc[4][0] = fmaf(wvb.x, sv.x, acc[4][0]); acc[4][1] = fmaf(wvb.x, sv.y, acc[4][1]);
      acc[4][2] = fmaf(wvb.x, sv.z, acc[4][2]); acc[4][3] = fmaf(wvb.x, sv.w, acc[4][3]);
      acc[5][0] = fmaf(wvb.y, sv.x, acc[5][0]); acc[5][1] = fmaf(wvb.y, sv.y, acc[5][1]);
      acc[5][2] = fmaf(wvb.y, sv.z, acc[5][2]); acc[5][3] = fmaf(wvb.y, sv.w, acc[5][3]);
      acc[6][0] = fmaf(wvb.z, sv.x, acc[6][0]); acc[6][1] = fmaf(wvb.z, sv.y, acc[6][1]);
      acc[6][2] = fmaf(wvb.z, sv.z, acc[6][2]); acc[6][3] = fmaf(wvb.z, sv.w, acc[6][3]);
      acc[7][0] = fmaf(wvb.w, sv.x, acc[7][0]); acc[7][1] = fmaf(wvb.w, sv.y, acc[7][1]);
      acc[7][2] = fmaf(wvb.w, sv.z, acc[7][2]); acc[7][3] = fmaf(wvb.w, sv.w, acc[7][3]);
    }
  }

  // write partials: part2[ks][b][o][h*64+w]
  float* pb = part2 + ((size_t)ks * BB * COUTC) * 4096;
#pragma unroll
  for (int i = 0; i < 8; i++) {
    float4 o;
    o.x = acc[i][0]; o.y = acc[i][1]; o.z = acc[i][2]; o.w = acc[i][3];
    *(float4*)&pb[((b * COUTC + co0 + i) * HH + h) * WW + w0] = o;
  }
}

// ---------------- K2r: sum 4 partials + bias -> out1
__global__ __launch_bounds__(256) void k2r(const float* __restrict__ part2,
                                           const float* __restrict__ dcn_b,
                                           float* __restrict__ out1) {
  int tid = blockIdx.x * 256 + threadIdx.x;
  if (tid >= BB * COUTC * HH * WW) return;
  int o = (tid >> 12) & 127;
  const int S = BB * COUTC * 4096;
  out1[tid] = part2[tid] + part2[tid + S] + part2[tid + 2 * S] + part2[tid + 3 * S] + dcn_b[o];
}

// ---------------- K3/K5: per-channel two-pass BN stats
__global__ __launch_bounds__(256) void k3_stats1(const float* __restrict__ out1,
                                                 const float* __restrict__ g, const float* __restrict__ bt,
                                                 float* __restrict__ scale, float* __restrict__ shift) {
  int c = blockIdx.x, t = threadIdx.x;
  __shared__ float r1[256];
  __shared__ float muS;
  float s = 0.f;
  for (int e = t; e < BB * HH * WW; e += 256) {
    int b = e >> 12, sp = e & 4095;
    s += out1[(b * COUTC + c) * 4096 + sp];
  }
  r1[t] = s;
  __syncthreads();
  for (int off = 128; off > 0; off >>= 1) {
    if (t < off) r1[t] += r1[t + off];
    __syncthreads();
  }
  if (t == 0) muS = r1[0] / 16384.f;
  __syncthreads();
  float mu = muS;
  __syncthreads();
  float s2 = 0.f;
  for (int e = t; e < BB * HH * WW; e += 256) {
    int b = e >> 12, sp = e & 4095;
    float d = out1[(b * COUTC + c) * 4096 + sp] - mu;
    s2 += d * d;
  }
  r1[t] = s2;
  __syncthreads();
  for (int off = 128; off > 0; off >>= 1) {
    if (t < off) r1[t] += r1[t + off];
    __syncthreads();
  }
  if (t == 0) {
    float var = r1[0] / 16384.f;
    float sc = g[c] * rsqrtf(var + 1e-5f);
    scale[c] = sc;
    shift[c] = bt[c] - mu * sc;
  }
}

__global__ __launch_bounds__(256) void k5_stats2(const float* __restrict__ out2,
                                                 const float* __restrict__ g, const float* __restrict__ bt,
                                                 float* __restrict__ scale, float* __restrict__ shift) {
  int c = blockIdx.x, t = threadIdx.x;
  __shared__ float r1[256];
  __shared__ float muS;
  float s = 0.f;
  for (int e = t; e < BB * OHH * OWW; e += 256) {
    int b = e >> 14, sp = e & 16383;
    s += out2[(b * COUTC + c) * 16384 + sp];
  }
  r1[t] = s;
  __syncthreads();
  for (int off = 128; off > 0; off >>= 1) {
    if (t < off) r1[t] += r1[t + off];
    __syncthreads();
  }
  if (t == 0) muS = r1[0] / 65536.f;
  __syncthreads();
  float mu = muS;
  __syncthreads();
  float s2 = 0.f;
  for (int e = t; e < BB * OHH * OWW; e += 256) {
    int b = e >> 14, sp = e & 16383;
    float d = out2[(b * COUTC + c) * 16384 + sp] - mu;
    s2 += d * d;
  }
  r1[t] = s2;
  __syncthreads();
  for (int off = 128; off > 0; off >>= 1) {
    if (t < off) r1[t] += r1[t + off];
    __syncthreads();
  }
  if (t == 0) {
    float var = r1[0] / 65536.f;
    float sc = g[c] * rsqrtf(var + 1e-5f);
    scale[c] = sc;
    shift[c] = bt[c] - mu * sc;
  }
}

// ---------------- K4f: bn1+relu fused transposed conv (tiled, parity-decomposed).
__global__ __launch_bounds__(256) void k4f(const float* __restrict__ out1,
                                           const float* __restrict__ s1,
                                           const float* __restrict__ sh1,
                                           const float* __restrict__ wt4,
                                           float* __restrict__ out2) {
  int oh = blockIdx.x, b = blockIdx.y;
  __shared__ __align__(16) float ys[2 * 128 * 64];  // exactly 64 KiB
  int t = threadIdx.x;
  int t0 = oh & 1;

#pragma unroll
  for (int ti = 0; ti < 2; ti++) {
    int tt = t0 + 2 * ti;
    int m = (oh + tt - 2) / 2;
    bool rowok = (m >= 0 && m < 64);
    for (int e = t; e < 2048; e += 256) {
      int i = e >> 4;
      float4 v = make_float4(0.f, 0.f, 0.f, 0.f);
      if (rowok) {
        float4 r = *(const float4*)&out1[((b * COUTC + i) * HH + m) * WW + (e & 15) * 4];
        float sc = s1[i], sh = sh1[i];
        v.x = fmaxf(fmaf(r.x, sc, sh), 0.f);
        v.y = fmaxf(fmaf(r.y, sc, sh), 0.f);
        v.z = fmaxf(fmaf(r.z, sc, sh), 0.f);
        v.w = fmaxf(fmaf(r.w, sc, sh), 0.f);
      }
      *(float4*)&ys[ti * 8192 + e * 4] = v;
    }
  }
  __syncthreads();

  int o = t >> 1, half = t & 1;
  int nb = half * 32;
  float acc[64];
#pragma unroll
  for (int j = 0; j < 64; j++) acc[j] = 0.f;

  const float* wb0 = wt4 + ((t0 * 128) * 128 + o) * 4;
  const float* wb1 = wt4 + (((t0 + 2) * 128) * 128 + o) * 4;

  for (int i = 0; i < 128; i++) {
#pragma unroll
    for (int ti = 0; ti < 2; ti++) {
      float4 wv = *(const float4*)((ti ? wb1 : wb0) + i * 512);
      float W0 = wv.x, W1 = wv.y, W2 = wv.z, W3 = wv.w;

      const float* yb = &ys[ti * 8192 + i * 64 + nb];
      float yv[34];
#pragma unroll
      for (int j4 = 0; j4 < 8; j4++) {
        float4 q4 = *(const float4*)(yb + 4 * j4);
        yv[1 + 4 * j4] = q4.x; yv[2 + 4 * j4] = q4.y;
        yv[3 + 4 * j4] = q4.z; yv[4 + 4 * j4] = q4.w;
      }
      yv[0]  = half ? yb[-1] : 0.f;
      yv[33] = half ? 0.f : yb[32];
#pragma unroll
      for (int u = 0; u < 32; u++) {
        acc[2 * u]     = fmaf(W0, yv[u],     fmaf(W2, yv[u + 1], acc[2 * u]));
        acc[2 * u + 1] = fmaf(W1, yv[u + 1], fmaf(W3, yv[u + 2], acc[2 * u + 1]));
      }
    }
  }

  float* op = out2 + ((b * COUTC + o) * OHH + oh) * OWW + half * 64;
#pragma unroll
  for (int j4 = 0; j4 < 16; j4++) {
    float4 v;
    v.x = acc[4 * j4]; v.y = acc[4 * j4 + 1]; v.z = acc[4 * j4 + 2]; v.w = acc[4 * j4 + 3];
    *(float4*)&op[4 * j4] = v;
  }
}

// ---------------- K6: bn2+relu apply (f32 out)
__global__ __launch_bounds__(256) void k6s(const float* __restrict__ out2,
                                           const float* __restrict__ scale2,
                                           const float* __restrict__ shift2,
                                           float* __restrict__ outp) {
  int tid = blockIdx.x * 256 + threadIdx.x;
  if (tid >= BB * COUTC * OHH * OWW) return;
  int c = (tid >> 14) & 127;
  outp[tid] = fmaxf(fmaf(out2[tid], scale2[c], shift2[c]), 0.f);
}

// ---------------- launch
extern "C" void kernel_launch(void* const* d_in, const int* in_sizes, int n_in,
                              void* d_out, int out_size, void* d_ws, size_t ws_size,
                              hipStream_t stream) {
  const float* x     = (const float*)d_in[0];
  const float* off_w = (const float*)d_in[1];
  const float* off_b = (const float*)d_in[2];
  const float* dcn_w = (const float*)d_in[3];
  const float* dcn_b = (const float*)d_in[4];
  const float* bn1_g = (const float*)d_in[5];
  const float* bn1_b = (const float*)d_in[6];
  const float* up_w  = (const float*)d_in[7];
  const float* bn2_g = (const float*)d_in[8];
  const float* bn2_b = (const float*)d_in[9];

  float* ws = (float*)d_ws;
  float* pyg  = ws;                              // 147456
  float* pxg  = pyg + BB * 9 * HH * WW;          // 147456
  float* mg   = pxg + BB * 9 * HH * WW;          // 147456
  float* out1 = mg + BB * 9 * HH * WW;           // 2097152
  float* scale1 = out1 + BB * COUTC * HH * WW;   // 128
  float* shift1 = scale1 + 128;                  // 128
  float* out2 = shift1 + 128;                    // 8388608
  float* scale2 = out2 + BB * COUTC * OHH * OWW; // 128
  float* shift2 = scale2 + 128;                  // 128
  float* w_t = shift2 + 128;                     // 294912
  float* wt4 = w_t + COUTC * CINC * 9;           // 262144
  float* part2 = wt4 + 4 * COUTC * COUTC * 4;    // 4 * 2097152
  // k1 partials overlaid on out2 region (k1p/k1r complete before k4f writes out2)
  float* part = out2;

  const int N4 = BB * COUTC * OHH * OWW;  // 8388608
  const int N2 = BB * COUTC * HH * WW;    // 2097152
  const int N1 = BB * 27 * HH * WW;       // 442368

  k0t<<<(COUTC * CINC * 9 + 255) / 256, 256, 0, stream>>>(dcn_w, w_t);
  k0u<<<(4 * COUTC * COUTC * 4 + 255) / 256, 256, 0, stream>>>(up_w, wt4);
  k1p<<<dim3(4, 64, 4), 256, 0, stream>>>(x, off_w, part);
  k1r<<<(N1 + 255) / 256, 256, 0, stream>>>(part, off_b, pyg, pxg, mg);
  k2p<<<dim3(4, 64, 4), 256, 0, stream>>>(x, w_t, pyg, pxg, mg, part2);
  k2r<<<(N2 + 255) / 256, 256, 0, stream>>>(part2, dcn_b, out1);
  k3_stats1<<<COUTC, 256, 0, stream>>>(out1, bn1_g, bn1_b, scale1, shift1);
  k4f<<<dim3(128, 4), 256, 0, stream>>>(out1, scale1, shift1, wt4, out2);
  k5_stats2<<<COUTC, 256, 0, stream>>>(out2, bn2_g, bn2_b, scale2, shift2);
  k6s<<<(N4 + 255) / 256, 256, 0, stream>>>(out2, scale2, shift2, (float*)d_out);
}

// Round 12
// 579.258 us; speedup vs baseline: 1.3378x; 1.1109x over previous
//
#include <hip/hip_runtime.h>
#include <math.h>

// Problem constants
#define BB 4
#define CINC 256
#define COUTC 128
#define HH 64
#define WW 64
#define OHH 128
#define OWW 128

typedef unsigned short u16;
typedef __attribute__((ext_vector_type(8))) short bf16x8;
typedef __attribute__((ext_vector_type(4))) float f32x4;

__device__ __forceinline__ u16 f2bf(float f) {
  unsigned int u = __float_as_uint(f);
  unsigned int r = u + 0x7FFFu + ((u >> 16) & 1u);  // RNE
  return (u16)(r >> 16);
}

// ---------------- K0t: dcn_w [o][c*9+q] -> bf16 wA[o][q*256+c]  (K reordered so a
// 32-wide K-chunk has constant tap q; contiguous k for MFMA A-frags)
__global__ __launch_bounds__(256) void k0t(const float* __restrict__ dcn_w, u16* __restrict__ wA) {
  int tid = blockIdx.x * 256 + threadIdx.x;
  if (tid >= COUTC * CINC * 9) return;
  int o = tid / 2304;
  int ckr = tid - o * 2304;
  int q = ckr >> 8;
  int c = ckr & 255;
  wA[tid] = f2bf(dcn_w[o * 2304 + c * 9 + q]);
}

// ---------------- K0u: transpose up_w -> wt4[tt][i][o][s]
__global__ __launch_bounds__(256) void k0u(const float* __restrict__ up_w, float* __restrict__ wt4) {
  int tid = blockIdx.x * 256 + threadIdx.x;
  if (tid >= 4 * COUTC * COUTC * 4) return;
  int s = tid & 3;
  int o = (tid >> 2) & 127;
  int i = (tid >> 9) & 127;
  int tt = tid >> 16;
  wt4[tid] = up_w[((i * COUTC + o) * 4 + (3 - tt)) * 4 + (3 - s)];
}

// ---------------- K1p: offset conv split-K(8) partials. grid (8,64,4)=(cc,h,b), 256 thr.
__global__ __launch_bounds__(256) void k1p(const float* __restrict__ x,
                                           const float* __restrict__ off_w,
                                           float* __restrict__ part) {
  int cc = blockIdx.x, h = blockIdx.y, b = blockIdx.z;
  __shared__ float xs[3 * 32 * 66];
  int t = threadIdx.x;
  int tw = t & 63;
  int tg = __builtin_amdgcn_readfirstlane(t >> 6);

  float acc[7];
#pragma unroll
  for (int j = 0; j < 7; j++) acc[j] = 0.f;

  int c0 = cc * 32;
  for (int e = t; e < 3 * 32 * 66; e += 256) {
    int r = e / (32 * 66);
    int rem = e - r * (32 * 66);
    int c = rem / 66;
    int wi = rem - c * 66;
    int row = h - 1 + r;
    int col = wi - 1;
    float v = 0.f;
    if (row >= 0 && row < HH && col >= 0 && col < WW)
      v = x[((b * CINC + c0 + c) * HH + row) * WW + col];
    xs[(r * 32 + c) * 66 + wi] = v;
  }
  __syncthreads();
  for (int c = 0; c < 32; c++) {
    float xv[9];
#pragma unroll
    for (int r = 0; r < 3; r++)
#pragma unroll
      for (int dx = 0; dx < 3; dx++)
        xv[r * 3 + dx] = xs[(r * 32 + c) * 66 + tw + dx];
#pragma unroll
    for (int j = 0; j < 7; j++) {
      int oc = tg + 4 * j;
      if (oc < 27) {
        const float* wp = off_w + (oc * CINC + c0 + c) * 9;  // uniform -> s_load
#pragma unroll
        for (int q = 0; q < 9; q++) acc[j] = fmaf(xv[q], wp[q], acc[j]);
      }
    }
  }

#pragma unroll
  for (int j = 0; j < 7; j++) {
    int oc = tg + 4 * j;
    if (oc < 27)
      part[((cc * BB + b) * 27 + oc) * 4096 + h * 64 + tw] = acc[j];
  }
}

// ---------------- K1r: reduce 8 partials + bias -> py/px/m
__global__ __launch_bounds__(256) void k1r(const float* __restrict__ part,
                                           const float* __restrict__ off_b,
                                           float* __restrict__ pyg,
                                           float* __restrict__ pxg,
                                           float* __restrict__ mg) {
  int tid = blockIdx.x * 256 + threadIdx.x;
  if (tid >= BB * 27 * HH * WW) return;
  int w = tid & 63;
  int h = (tid >> 6) & 63;
  int oc = (tid >> 12) % 27;
  int b = tid / (27 * 4096);
  int sp = tid & 4095;

  float v = off_b[oc];
#pragma unroll
  for (int cc = 0; cc < 8; cc++)
    v += part[((cc * BB + b) * 27 + oc) * 4096 + sp];

  int k = oc % 9;
  int gi = ((b * 9 + k) * HH + h) * WW + w;
  if (oc < 9) {
    pyg[gi] = v + (float)(oc / 3) - 1.f + (float)h;
  } else if (oc < 18) {
    pxg[gi] = v + (float)((oc - 9) % 3) - 1.f + (float)w;
  } else {
    mg[gi] = 1.f / (1.f + expf(-v));
  }
}

// ---------------- gather helper: 2 channels x 4 corners
__device__ __forceinline__ void gather8(const float* __restrict__ p0,
                                        int sA0, int sA1, int sB0, int sB1,
                                        float* r) {
  r[0] = p0[sA0]; r[1] = p0[sA1]; r[2] = p0[sB0]; r[3] = p0[sB1];
  const float* p1 = p0 + 4096;
  r[4] = p1[sA0]; r[5] = p1[sA1]; r[6] = p1[sB0]; r[7] = p1[sB1];
}

// ---------------- K2m: deformable conv, split-K(4), bf16 MFMA GEMM.
// grid (4,64,4)=(ks,h,b). Block: 64 px x 128 cout x 64 ch. K reordered ck'=q*256+c:
// each 32-K chunk has constant tap q -> per-thread descriptors (by q, px=t&63) are
// chunk-invariant. Samples gathered f32, packed bf16 into transposed LDS tile
// scolT[px][ck] (stride 40: 16B-aligned b128 B-frags). Weights bf16 from L2 (A-frags).
// LDS double-buffered: ONE barrier per chunk. mfma_f32_16x16x32_bf16, C/D layout
// col=lane&15, row=quad*4+reg (m89-verified).
__global__ __launch_bounds__(256) void k2m(const float* __restrict__ x,
                                           const u16* __restrict__ wA,
                                           const float* __restrict__ pyg,
                                           const float* __restrict__ pxg,
                                           const float* __restrict__ mg,
                                           float* __restrict__ part2) {
  int ks = blockIdx.x, h = blockIdx.y, b = blockIdx.z;
  __shared__ __align__(16) u16 scolT[2][64 * 40];  // [px][ck] bf16, +8 pad
  int t = threadIdx.x;
  int px = t & 63;
  int wave = t >> 6;
  int lane15 = t & 15;
  int quad = (t >> 4) & 3;

  // ---- per-(q,px) bilinear descriptors (masked, m-premultiplied) ----
  float dw0[9], dw1[9], dw2[9], dw3[9];
  int doA[9], doB[9];
#pragma unroll
  for (int q = 0; q < 9; q++) {
    int gi = ((b * 9 + q) * HH + h) * WW + px;
    float py = pyg[gi], pxx = pxg[gi], m = mg[gi];
    float y0f = floorf(py), x0f = floorf(pxx);
    float wy = py - y0f, wx = pxx - x0f;
    int y0 = (int)y0f, x0 = (int)x0f;
    bool vy0 = (unsigned)y0 < 64u, vy1 = (unsigned)(y0 + 1) < 64u;
    bool vx0 = (unsigned)x0 < 64u, vx1 = (unsigned)(x0 + 1) < 64u;
    int y0c = min(max(y0, 0), 63), y1c = min(max(y0 + 1, 0), 63);
    int x0c = min(max(x0, 0), 63), x1c = min(max(x0 + 1, 0), 63);
    dw0[q] = (vy0 && vx0) ? (1.f - wy) * (1.f - wx) * m : 0.f;
    dw1[q] = (vy0 && vx1) ? (1.f - wy) * wx * m : 0.f;
    dw2[q] = (vy1 && vx0) ? wy * (1.f - wx) * m : 0.f;
    dw3[q] = (vy1 && vx1) ? wy * wx * m : 0.f;
    doA[q] = (y0c * 64 + x0c) | ((y0c * 64 + x1c) << 16);
    doB[q] = (y1c * 64 + x0c) | ((y1c * 64 + x1c) << 16);
  }

  f32x4 acc[8];
#pragma unroll
  for (int i = 0; i < 8; i++) acc[i] = (f32x4){0.f, 0.f, 0.f, 0.f};

  const float* xpb = x + b * CINC * 4096;
  const u16* wAr0 = wA + (wave * 32 + lane15) * 2304 + quad * 8;
  const u16* wAr1 = wAr0 + 16 * 2304;

  float rx[32];
  // prefetch chunk 0 (q=0, c0=ks*64)
  {
    int sA0 = doA[0] & 0xffff, sA1 = ((unsigned)doA[0]) >> 16;
    int sB0 = doB[0] & 0xffff, sB1 = ((unsigned)doB[0]) >> 16;
#pragma unroll
    for (int j2 = 0; j2 < 4; j2++)
      gather8(xpb + (ks * 64 + 2 * (wave + 4 * j2)) * 4096, sA0, sA1, sB0, sB1, &rx[8 * j2]);
  }

#pragma unroll
  for (int ci = 0; ci < 18; ci++) {
    int q = ci >> 1;
    // combine prefetched gathers -> bf16 pack -> LDS buf[ci&1]
    u16* sb = &scolT[ci & 1][0];
#pragma unroll
    for (int j2 = 0; j2 < 4; j2++) {
      int u = wave + 4 * j2;
      float vA = dw0[q] * rx[8 * j2 + 0] + dw1[q] * rx[8 * j2 + 1] +
                 dw2[q] * rx[8 * j2 + 2] + dw3[q] * rx[8 * j2 + 3];
      float vB = dw0[q] * rx[8 * j2 + 4] + dw1[q] * rx[8 * j2 + 5] +
                 dw2[q] * rx[8 * j2 + 6] + dw3[q] * rx[8 * j2 + 7];
      *(unsigned*)&sb[px * 40 + 2 * u] = (unsigned)f2bf(vA) | ((unsigned)f2bf(vB) << 16);
    }
    // issue next chunk's gathers (land during barrier+MFMA)
    if (ci < 17) {
      int qn = (ci + 1) >> 1;
      int c0n = ks * 64 + ((ci + 1) & 1) * 32;
      int sA0 = doA[qn] & 0xffff, sA1 = ((unsigned)doA[qn]) >> 16;
      int sB0 = doB[qn] & 0xffff, sB1 = ((unsigned)doB[qn]) >> 16;
#pragma unroll
      for (int j2 = 0; j2 < 4; j2++)
        gather8(xpb + (c0n + 2 * (wave + 4 * j2)) * 4096, sA0, sA1, sB0, sB1, &rx[8 * j2]);
    }
    __syncthreads();  // buf[ci&1] visible; prev reads of buf[(ci-1)&1] drained
    // MFMA: 2 cout rows x 4 px tiles
    int kb = q * 256 + ks * 64 + (ci & 1) * 32;
    bf16x8 a0 = *(const bf16x8*)(wAr0 + kb);
    bf16x8 a1 = *(const bf16x8*)(wAr1 + kb);
    const u16* sr = &scolT[ci & 1][lane15 * 40 + quad * 8];
    bf16x8 b0 = *(const bf16x8*)(sr);
    bf16x8 b1 = *(const bf16x8*)(sr + 16 * 40);
    bf16x8 b2 = *(const bf16x8*)(sr + 32 * 40);
    bf16x8 b3 = *(const bf16x8*)(sr + 48 * 40);
    acc[0] = __builtin_amdgcn_mfma_f32_16x16x32_bf16(a0, b0, acc[0], 0, 0, 0);
    acc[1] = __builtin_amdgcn_mfma_f32_16x16x32_bf16(a0, b1, acc[1], 0, 0, 0);
    acc[2] = __builtin_amdgcn_mfma_f32_16x16x32_bf16(a0, b2, acc[2], 0, 0, 0);
    acc[3] = __builtin_amdgcn_mfma_f32_16x16x32_bf16(a0, b3, acc[3], 0, 0, 0);
    acc[4] = __builtin_amdgcn_mfma_f32_16x16x32_bf16(a1, b0, acc[4], 0, 0, 0);
    acc[5] = __builtin_amdgcn_mfma_f32_16x16x32_bf16(a1, b1, acc[5], 0, 0, 0);
    acc[6] = __builtin_amdgcn_mfma_f32_16x16x32_bf16(a1, b2, acc[6], 0, 0, 0);
    acc[7] = __builtin_amdgcn_mfma_f32_16x16x32_bf16(a1, b3, acc[7], 0, 0, 0);
  }

  // write partials: part2[ks][b][o][h][w]; C/D: col=lane&15 (px), row=quad*4+i (o)
  float* pb = part2 + (size_t)ks * BB * COUTC * 4096;
#pragma unroll
  for (int tr = 0; tr < 2; tr++)
#pragma unroll
    for (int pc = 0; pc < 4; pc++) {
      f32x4 a = acc[tr * 4 + pc];
      int ob = wave * 32 + tr * 16 + quad * 4;
#pragma unroll
      for (int i = 0; i < 4; i++)
        pb[((b * COUTC + ob + i) * HH + h) * WW + pc * 16 + lane15] = a[i];
    }
}

// ---------------- K2r: sum 4 partials + bias -> out1
__global__ __launch_bounds__(256) void k2r(const float* __restrict__ part2,
                                           const float* __restrict__ dcn_b,
                                           float* __restrict__ out1) {
  int tid = blockIdx.x * 256 + threadIdx.x;
  if (tid >= BB * COUTC * HH * WW) return;
  int o = (tid >> 12) & 127;
  const int S = BB * COUTC * 4096;
  out1[tid] = part2[tid] + part2[tid + S] + part2[tid + 2 * S] + part2[tid + 3 * S] + dcn_b[o];
}

// ---------------- K3/K5: per-channel two-pass BN stats
__global__ __launch_bounds__(256) void k3_stats1(const float* __restrict__ out1,
                                                 const float* __restrict__ g, const float* __restrict__ bt,
                                                 float* __restrict__ scale, float* __restrict__ shift) {
  int c = blockIdx.x, t = threadIdx.x;
  __shared__ float r1[256];
  __shared__ float muS;
  float s = 0.f;
  for (int e = t; e < BB * HH * WW; e += 256) {
    int b = e >> 12, sp = e & 4095;
    s += out1[(b * COUTC + c) * 4096 + sp];
  }
  r1[t] = s;
  __syncthreads();
  for (int off = 128; off > 0; off >>= 1) {
    if (t < off) r1[t] += r1[t + off];
    __syncthreads();
  }
  if (t == 0) muS = r1[0] / 16384.f;
  __syncthreads();
  float mu = muS;
  __syncthreads();
  float s2 = 0.f;
  for (int e = t; e < BB * HH * WW; e += 256) {
    int b = e >> 12, sp = e & 4095;
    float d = out1[(b * COUTC + c) * 4096 + sp] - mu;
    s2 += d * d;
  }
  r1[t] = s2;
  __syncthreads();
  for (int off = 128; off > 0; off >>= 1) {
    if (t < off) r1[t] += r1[t + off];
    __syncthreads();
  }
  if (t == 0) {
    float var = r1[0] / 16384.f;
    float sc = g[c] * rsqrtf(var + 1e-5f);
    scale[c] = sc;
    shift[c] = bt[c] - mu * sc;
  }
}

__global__ __launch_bounds__(256) void k5_stats2(const float* __restrict__ out2,
                                                 const float* __restrict__ g, const float* __restrict__ bt,
                                                 float* __restrict__ scale, float* __restrict__ shift) {
  int c = blockIdx.x, t = threadIdx.x;
  __shared__ float r1[256];
  __shared__ float muS;
  float s = 0.f;
  for (int e = t; e < BB * OHH * OWW; e += 256) {
    int b = e >> 14, sp = e & 16383;
    s += out2[(b * COUTC + c) * 16384 + sp];
  }
  r1[t] = s;
  __syncthreads();
  for (int off = 128; off > 0; off >>= 1) {
    if (t < off) r1[t] += r1[t + off];
    __syncthreads();
  }
  if (t == 0) muS = r1[0] / 65536.f;
  __syncthreads();
  float mu = muS;
  __syncthreads();
  float s2 = 0.f;
  for (int e = t; e < BB * OHH * OWW; e += 256) {
    int b = e >> 14, sp = e & 16383;
    float d = out2[(b * COUTC + c) * 16384 + sp] - mu;
    s2 += d * d;
  }
  r1[t] = s2;
  __syncthreads();
  for (int off = 128; off > 0; off >>= 1) {
    if (t < off) r1[t] += r1[t + off];
    __syncthreads();
  }
  if (t == 0) {
    float var = r1[0] / 65536.f;
    float sc = g[c] * rsqrtf(var + 1e-5f);
    scale[c] = sc;
    shift[c] = bt[c] - mu * sc;
  }
}

// ---------------- K4f: bn1+relu fused transposed conv (tiled, parity-decomposed).
__global__ __launch_bounds__(256) void k4f(const float* __restrict__ out1,
                                           const float* __restrict__ s1,
                                           const float* __restrict__ sh1,
                                           const float* __restrict__ wt4,
                                           float* __restrict__ out2) {
  int oh = blockIdx.x, b = blockIdx.y;
  __shared__ __align__(16) float ys[2 * 128 * 64];  // exactly 64 KiB
  int t = threadIdx.x;
  int t0 = oh & 1;

#pragma unroll
  for (int ti = 0; ti < 2; ti++) {
    int tt = t0 + 2 * ti;
    int m = (oh + tt - 2) / 2;
    bool rowok = (m >= 0 && m < 64);
    for (int e = t; e < 2048; e += 256) {
      int i = e >> 4;
      float4 v = make_float4(0.f, 0.f, 0.f, 0.f);
      if (rowok) {
        float4 r = *(const float4*)&out1[((b * COUTC + i) * HH + m) * WW + (e & 15) * 4];
        float sc = s1[i], sh = sh1[i];
        v.x = fmaxf(fmaf(r.x, sc, sh), 0.f);
        v.y = fmaxf(fmaf(r.y, sc, sh), 0.f);
        v.z = fmaxf(fmaf(r.z, sc, sh), 0.f);
        v.w = fmaxf(fmaf(r.w, sc, sh), 0.f);
      }
      *(float4*)&ys[ti * 8192 + e * 4] = v;
    }
  }
  __syncthreads();

  int o = t >> 1, half = t & 1;
  int nb = half * 32;
  float acc[64];
#pragma unroll
  for (int j = 0; j < 64; j++) acc[j] = 0.f;

  const float* wb0 = wt4 + ((t0 * 128) * 128 + o) * 4;
  const float* wb1 = wt4 + (((t0 + 2) * 128) * 128 + o) * 4;

  for (int i = 0; i < 128; i++) {
#pragma unroll
    for (int ti = 0; ti < 2; ti++) {
      float4 wv = *(const float4*)((ti ? wb1 : wb0) + i * 512);
      float W0 = wv.x, W1 = wv.y, W2 = wv.z, W3 = wv.w;

      const float* yb = &ys[ti * 8192 + i * 64 + nb];
      float yv[34];
#pragma unroll
      for (int j4 = 0; j4 < 8; j4++) {
        float4 q4 = *(const float4*)(yb + 4 * j4);
        yv[1 + 4 * j4] = q4.x; yv[2 + 4 * j4] = q4.y;
        yv[3 + 4 * j4] = q4.z; yv[4 + 4 * j4] = q4.w;
      }
      yv[0]  = half ? yb[-1] : 0.f;
      yv[33] = half ? 0.f : yb[32];
#pragma unroll
      for (int u = 0; u < 32; u++) {
        acc[2 * u]     = fmaf(W0, yv[u],     fmaf(W2, yv[u + 1], acc[2 * u]));
        acc[2 * u + 1] = fmaf(W1, yv[u + 1], fmaf(W3, yv[u + 2], acc[2 * u + 1]));
      }
    }
  }

  float* op = out2 + ((b * COUTC + o) * OHH + oh) * OWW + half * 64;
#pragma unroll
  for (int j4 = 0; j4 < 16; j4++) {
    float4 v;
    v.x = acc[4 * j4]; v.y = acc[4 * j4 + 1]; v.z = acc[4 * j4 + 2]; v.w = acc[4 * j4 + 3];
    *(float4*)&op[4 * j4] = v;
  }
}

// ---------------- K6: bn2+relu apply (f32 out)
__global__ __launch_bounds__(256) void k6s(const float* __restrict__ out2,
                                           const float* __restrict__ scale2,
                                           const float* __restrict__ shift2,
                                           float* __restrict__ outp) {
  int tid = blockIdx.x * 256 + threadIdx.x;
  if (tid >= BB * COUTC * OHH * OWW) return;
  int c = (tid >> 14) & 127;
  outp[tid] = fmaxf(fmaf(out2[tid], scale2[c], shift2[c]), 0.f);
}

// ---------------- launch
extern "C" void kernel_launch(void* const* d_in, const int* in_sizes, int n_in,
                              void* d_out, int out_size, void* d_ws, size_t ws_size,
                              hipStream_t stream) {
  const float* x     = (const float*)d_in[0];
  const float* off_w = (const float*)d_in[1];
  const float* off_b = (const float*)d_in[2];
  const float* dcn_w = (const float*)d_in[3];
  const float* dcn_b = (const float*)d_in[4];
  const float* bn1_g = (const float*)d_in[5];
  const float* bn1_b = (const float*)d_in[6];
  const float* up_w  = (const float*)d_in[7];
  const float* bn2_g = (const float*)d_in[8];
  const float* bn2_b = (const float*)d_in[9];

  float* ws = (float*)d_ws;
  float* pyg  = ws;                              // 147456
  float* pxg  = pyg + BB * 9 * HH * WW;          // 147456
  float* mg   = pxg + BB * 9 * HH * WW;          // 147456
  float* out1 = mg + BB * 9 * HH * WW;           // 2097152
  float* scale1 = out1 + BB * COUTC * HH * WW;   // 128
  float* shift1 = scale1 + 128;                  // 128
  float* out2 = shift1 + 128;                    // 8388608
  float* scale2 = out2 + BB * COUTC * OHH * OWW; // 128
  float* shift2 = scale2 + 128;                  // 128
  float* w_t = shift2 + 128;                     // 294912 floats reserved (wA uses half as u16)
  float* wt4 = w_t + COUTC * CINC * 9;           // 262144
  float* part2 = wt4 + 4 * COUTC * COUTC * 4;    // 4 * 2097152
  u16* wA = (u16*)w_t;                           // 128*2304 bf16
  // k1 partials (8*4*27*4096 = 3.5M floats) overlaid on out2 region
  float* part = out2;

  const int N4 = BB * COUTC * OHH * OWW;  // 8388608
  const int N2 = BB * COUTC * HH * WW;    // 2097152
  const int N1 = BB * 27 * HH * WW;       // 442368

  k0t<<<(COUTC * CINC * 9 + 255) / 256, 256, 0, stream>>>(dcn_w, wA);
  k0u<<<(4 * COUTC * COUTC * 4 + 255) / 256, 256, 0, stream>>>(up_w, wt4);
  k1p<<<dim3(8, 64, 4), 256, 0, stream>>>(x, off_w, part);
  k1r<<<(N1 + 255) / 256, 256, 0, stream>>>(part, off_b, pyg, pxg, mg);
  k2m<<<dim3(4, 64, 4), 256, 0, stream>>>(x, wA, pyg, pxg, mg, part2);
  k2r<<<(N2 + 255) / 256, 256, 0, stream>>>(part2, dcn_b, out1);
  k3_stats1<<<COUTC, 256, 0, stream>>>(out1, bn1_g, bn1_b, scale1, shift1);
  k4f<<<dim3(128, 4), 256, 0, stream>>>(out1, scale1, shift1, wt4, out2);
  k5_stats2<<<COUTC, 256, 0, stream>>>(out2, bn2_g, bn2_b, scale2, shift2);
  k6s<<<(N4 + 255) / 256, 256, 0, stream>>>(out2, scale2, shift2, (float*)d_out);
}